// Round 26
// baseline (298.869 us; speedup 1.0000x reference)
//
#include <hip/hip_runtime.h>
#include <hip/hip_fp16.h>

static constexpr int NB = 128;
static constexpr int NT = 256;
static constexpr int NV = 64;
static constexpr int NBT = NB * NT;       // 32768
static constexpr int NBTV = NBT * NV;     // 2097152

typedef __attribute__((ext_vector_type(8))) short short8;
typedef __attribute__((ext_vector_type(4))) float f32x4;
typedef __attribute__((ext_vector_type(4))) float fvec4;

__device__ __forceinline__ void wave_lds_fence() {
    __builtin_amdgcn_sched_barrier(0);
    asm volatile("s_waitcnt lgkmcnt(0)" ::: "memory");
    __builtin_amdgcn_sched_barrier(0);
}

// cross-wave barrier with LDS visibility, WITHOUT vmcnt drain.
__device__ __forceinline__ void block_sync_lds() {
    __builtin_amdgcn_sched_barrier(0);
    asm volatile("s_waitcnt lgkmcnt(0)" ::: "memory");
    __builtin_amdgcn_s_barrier();
    asm volatile("" ::: "memory");
    __builtin_amdgcn_sched_barrier(0);
}

__device__ __forceinline__ unsigned short f2bf(float x) {
    unsigned int u = __float_as_uint(x);
    return (unsigned short)((u + 0x7FFFu + ((u >> 16) & 1u)) >> 16);
}
__device__ __forceinline__ float bf2f(unsigned short b) {
    return __uint_as_float(((unsigned int)b) << 16);
}
__device__ __forceinline__ unsigned short f2h(float x) {
    union { _Float16 h; unsigned short u; } c; c.h = (_Float16)x; return c.u;
}
__device__ __forceinline__ float fsigm(float x) {
    return __builtin_amdgcn_rcpf(1.0f + __expf(-x));
}
__device__ __forceinline__ float ftanh(float x) {
    return 1.0f - 2.0f * __builtin_amdgcn_rcpf(1.0f + __expf(2.0f * x));
}

__device__ __forceinline__ short8 pack8(float4 a, float4 b) {
    short8 r;
    r[0] = (short)f2bf(a.x); r[1] = (short)f2bf(a.y); r[2] = (short)f2bf(a.z); r[3] = (short)f2bf(a.w);
    r[4] = (short)f2bf(b.x); r[5] = (short)f2bf(b.y); r[6] = (short)f2bf(b.z); r[7] = (short)f2bf(b.w);
    return r;
}

__device__ __forceinline__ void dot4(float4& acc, const float4 wv, const float4 xv) {
    acc.x = fmaf(wv.x, xv.x, acc.x);
    acc.y = fmaf(wv.y, xv.y, acc.y);
    acc.z = fmaf(wv.z, xv.z, acc.z);
    acc.w = fmaf(wv.w, xv.w, acc.w);
}

// ---------------- K_prep: weight conversions only (512 blocks) ----------------
__global__ __launch_bounds__(256) void k_prep(
    const float* __restrict__ Wf, const float* __restrict__ Wihf,
    const float* __restrict__ Wihb, const float* __restrict__ Wihg,
    const float* __restrict__ Whhf, const float* __restrict__ Whhb,
    const float* __restrict__ Whhg, const float* __restrict__ Wri,
    const float* __restrict__ Wfu,
    unsigned short* __restrict__ wbf, float* __restrict__ wdiag,
    unsigned short* __restrict__ wgf, unsigned short* __restrict__ wgb,
    unsigned short* __restrict__ wgg,
    unsigned short* __restrict__ whhf_h, unsigned short* __restrict__ whhb_h,
    unsigned short* __restrict__ whhg_h,
    unsigned short* __restrict__ wri_bf, unsigned short* __restrict__ wfu_bf) {
    int i = blockIdx.x * 256 + threadIdx.x;
    if (i < NV * 32 * NV) wbf[i] = f2bf(Wf[i]);
    if (i < 2048) wdiag[i] = bf2f(f2bf(Wf[i * 64 + (i >> 5)]));
    if (i < 32768) {
        int n = i >> 7, k = i & 127;
        wgf[i] = f2bf(Wihf[n * 192 + k]);
        wgb[i] = f2bf(Wihb[n * 192 + k]);
    }
    if (i < 12288) wgg[i] = f2bf(Wihg[i]);
    if (i < 16384) { whhf_h[i] = f2h(Whhf[i]); whhb_h[i] = f2h(Whhb[i]); }
    if (i < 3072) whhg_h[i] = f2h(Whhg[i]);
    if (i < 8192) { wri_bf[i] = f2bf(Wri[i]); wfu_bf[i] = f2bf(Wfu[i]); }
}

// ---------------- K2: stats + forward-fill + decay + x_complete + GRU gate GEMM ----------------
__global__ __launch_bounds__(256) void k_fill(
    const int* __restrict__ lengths,
    const float* __restrict__ values, const float* __restrict__ masks,
    const float* __restrict__ deltas, const float* __restrict__ minv,
    const float* __restrict__ maxv,
    const float* __restrict__ Wd, const float* __restrict__ bd,
    float* __restrict__ stats,
    float* __restrict__ mmn_ws, float* __restrict__ nmeans_ws,
    float* __restrict__ xcomp, unsigned short* __restrict__ gam,
    const unsigned short* __restrict__ wgg, const float* __restrict__ bihg,
    float* __restrict__ gg) {
    int b = blockIdx.x; int tid = threadIdx.x;
    int v = tid & 63; int tc = tid >> 6;
    float mn = minv[b * NV + v];
    size_t base = (size_t)b * NT * NV + v;
    __shared__ float red[3][4][64];
    __shared__ float lastv[4][64];
    __shared__ int hasf[4][64];
    __shared__ float nv0s[64];
    __shared__ float smm[64], snm[64];
    __shared__ __align__(16) unsigned short sxc[256][64];   // bf16 xcomp tile (32 KB)
    int t0 = tc * 64;
    float sv = 0.f, sq = 0.f, sm = 0.f;
    float last = 0.f; int has = 0;
    for (int t = t0; t < t0 + 64; t++) {
        float val = values[base + (size_t)t * NV];
        float m = masks[base + (size_t)t * NV];
        sv += val; sq += val * val; sm += m;
        if (m != 0.f) { last = val; has = 1; }
        if (tc == 0 && t == 0) nv0s[v] = val;
    }
    red[0][tc][v] = sv; red[1][tc][v] = sq; red[2][tc][v] = sm;
    lastv[tc][v] = last; hasf[tc][v] = has;
    __syncthreads();
    if (tc == 0) {
        sv = red[0][0][v] + red[0][1][v] + red[0][2][v] + red[0][3][v];
        sq = red[1][0][v] + red[1][1][v] + red[1][2][v] + red[1][3][v];
        sm = red[2][0][v] + red[2][1][v] + red[2][2][v] + red[2][3][v];
        float mean = sv / sm;
        float var = (sq - 2.0f * mean * sv + (float)NT * mean * mean) / (sm - 1.0f);
        var = fmaxf(var, 0.0f);
        float sd = sqrtf(var);
        float lf = (float)lengths[b];
        float miss = 1.0f - sm / lf;
        float mx = maxv[b * NV + v];
        float mm = fmaxf(mx - mn, 1e-8f);
        float* st = stats + b * 256;
        if (v == 0) st[0] = lf;
        st[1 + v] = mean; st[65 + v] = sd; st[129 + v] = miss;
        float nmean = (mean - mn) / mm;
        mmn_ws[b * NV + v] = mm;
        nmeans_ws[b * NV + v] = nmean;
        smm[v] = mm; snm[v] = nmean;
    }
    __syncthreads();
    float mm = smm[v];
    float nmean = snm[v];
    float wd = Wd[v * NV + v], bdv = bd[v];
    float xp = (nv0s[v] - mn) / mm;
    for (int q = tc - 1; q >= 0; q--) {
        if (hasf[q][v]) { xp = (lastv[q][v] - mn) / mm; break; }
    }
    for (int t = t0; t < t0 + 64; t++) {
        size_t i = base + (size_t)t * NV;
        float val = values[i], m = masks[i], d = deltas[i];
        float nv = (val - mn) / mm;
        float g = expf(-fmaxf(fmaf(d, wd, bdv), 0.0f));
        float xd = g * xp + (1.0f - g) * nmean;
        float xc = m * nv + (1.0f - m) * xd;
        xcomp[i] = xc; gam[i] = f2bf(g);
        sxc[t][v] = f2bf(xc);
        xp = (m != 0.f) ? nv : xp;
    }
    __syncthreads();
    // ---- GRU input-gate GEMM for this sample (4 tiles per wave) ----
    int lane = tid & 63;
    int r = lane & 15, kc = lane >> 4;
    for (int tile = 0; tile < 4; tile++) {
        int trow = (tc * 4 + tile) * 16;
        int bt0 = b * NT + trow;
        short8 af0 = *(const short8*)&sxc[trow + r][kc * 8];
        short8 af1 = *(const short8*)&sxc[trow + r][32 + kc * 8];
        const float* mr = masks + ((size_t)bt0 + r) * NV + kc * 8;
        short8 af2 = pack8(*(const float4*)(mr), *(const float4*)(mr + 4));
        short8 af3 = pack8(*(const float4*)(mr + 32), *(const float4*)(mr + 36));
        #pragma unroll 3
        for (int nt = 0; nt < 6; nt++) {
            const unsigned short* w = wgg + (size_t)(nt * 16 + r) * 128 + kc * 8;
            float bias = bihg[nt * 16 + r];
            f32x4 acc = {bias, bias, bias, bias};
            acc = __builtin_amdgcn_mfma_f32_16x16x32_bf16(af0, *(const short8*)(w), acc, 0, 0, 0);
            acc = __builtin_amdgcn_mfma_f32_16x16x32_bf16(af1, *(const short8*)(w + 32), acc, 0, 0, 0);
            acc = __builtin_amdgcn_mfma_f32_16x16x32_bf16(af2, *(const short8*)(w + 64), acc, 0, 0, 0);
            acc = __builtin_amdgcn_mfma_f32_16x16x32_bf16(af3, *(const short8*)(w + 96), acc, 0, 0, 0);
            #pragma unroll
            for (int i = 0; i < 4; i++)
                gg[(size_t)(bt0 + kc * 4 + i) * 96 + nt * 16 + r] = acc[i];
        }
    }
}

// ---------------- GRU step ----------------
#define GRU_STEP(T, GIN) { \
    const int t_ = (T); const int p_ = t_ & 1; \
    int4 raw_[4]; \
    const int4* hp_ = (const int4*)hsg[g][s]; \
    _Pragma("unroll") for (int q = 0; q < 4; q++) raw_[q] = hp_[q]; \
    const __half2* hhv_ = (const __half2*)raw_; \
    __half2 a0_ = zh2, a1_ = zh2, a2_ = zh2, a3_ = zh2; \
    _Pragma("unroll") for (int q = 0; q < 16; q += 4) { \
        a0_ = __hfma2(w2[q],     hhv_[q],     a0_); \
        a1_ = __hfma2(w2[q + 1], hhv_[q + 1], a1_); \
        a2_ = __hfma2(w2[q + 2], hhv_[q + 2], a2_); \
        a3_ = __hfma2(w2[q + 3], hhv_[q + 3], a3_); } \
    __half2 sA_ = __hadd2(__hadd2(a0_, a1_), __hadd2(a2_, a3_)); \
    float d_ = __low2float(sA_) + __high2float(sA_); \
    if (g < 2) { \
        gexg[p_][s][n][g] = GIN + bh + d_; \
    } else { \
        gexg[p_][s][n][2] = bh + d_; \
        gexg[p_][s][n][3] = GIN; \
    } \
    block_sync_lds(); \
    float qx_ = gexg[p_][s][n][0], qy_ = gexg[p_][s][n][1]; \
    float qz_ = gexg[p_][s][n][2], qw_ = gexg[p_][s][n][3]; \
    float rr_ = fsigm(qx_); \
    float zz_ = fsigm(qy_); \
    float nn_ = ftanh(qw_ + rr_ * qz_); \
    float h_ = (1.f - zz_) * nn_ + zz_ * hprev; \
    hprev = h_; \
    if (t_ < len) hn = h_; \
    hsg[g][s][n] = f2h(h_); \
    wave_lds_fence(); \
}

// feat MLP body, per-wave independent
#define FEAT_BODY(BT0) { \
    int bt0 = (BT0); \
    int r = lane & 15, kc = lane >> 4; \
    unsigned short* hbw = hbs[wave]; \
    float* lx = ldsx[wave]; \
    float* flw = fls[wave]; \
    short8 a0, a1; \
    { \
        const float* xr = xcomp + (size_t)(bt0 + r) * NV + kc * 8; \
        a0 = pack8(*(const float4*)(xr), *(const float4*)(xr + 4)); \
        a1 = pack8(*(const float4*)(xr + 32), *(const float4*)(xr + 36)); \
    } \
    { \
        int gc0 = kc * 16; \
        const float* xr2 = xcomp + (size_t)(bt0 + r) * NV + gc0; \
        _Pragma("unroll") for (int e = 0; e < 16; e += 4) { \
            float4 p = *(const float4*)(xr2 + e); \
            lx[(gc0 + e + 0) * 16 + r] = bf2f(f2bf(p.x)); \
            lx[(gc0 + e + 1) * 16 + r] = bf2f(f2bf(p.y)); \
            lx[(gc0 + e + 2) * 16 + r] = bf2f(f2bf(p.z)); \
            lx[(gc0 + e + 3) * 16 + r] = bf2f(f2bf(p.w)); \
        } \
    } \
    short8 wb0, wb1; \
    { \
        const float* w = Wnl1 + r * 32 + kc * 8; \
        wb0 = pack8(*(const float4*)w, *(const float4*)(w + 4)); \
        const float* w2p = Wnl1 + (16 + r) * 32 + kc * 8; \
        wb1 = pack8(*(const float4*)w2p, *(const float4*)(w2p + 4)); \
    } \
    float b0i[4], b1i[4], w2a[4], w2b[4]; \
    _Pragma("unroll") for (int i = 0; i < 4; i++) { \
        b0i[i] = bnl1[kc * 4 + i]; \
        b1i[i] = bnl1[16 + kc * 4 + i]; \
        w2a[i] = Wnl2[kc * 4 + i]; \
        w2b[i] = Wnl2[16 + kc * 4 + i]; \
    } \
    float bn2 = bnl2[0]; \
    __builtin_amdgcn_wave_barrier(); \
    _Pragma("unroll 2") for (int g = 0; g < 64; g++) { \
        __builtin_amdgcn_wave_barrier(); \
        float xv[4]; \
        _Pragma("unroll") for (int i = 0; i < 4; i++) xv[i] = lx[g * 16 + kc * 4 + i]; \
        _Pragma("unroll") for (int f = 0; f < 2; f++) { \
            int n0 = g * 32 + f * 16; \
            const unsigned short* wrow = wbf + (size_t)(n0 + r) * 64; \
            short8 b0 = *(const short8*)(wrow + kc * 8); \
            short8 b1 = *(const short8*)(wrow + 32 + kc * 8); \
            f32x4 acc = {0.f, 0.f, 0.f, 0.f}; \
            acc = __builtin_amdgcn_mfma_f32_16x16x32_bf16(a0, b0, acc, 0, 0, 0); \
            acc = __builtin_amdgcn_mfma_f32_16x16x32_bf16(a1, b1, acc, 0, 0, 0); \
            int n = n0 + r; \
            float wd = wdiag[n], bs = bfeat[n]; \
            _Pragma("unroll") for (int i = 0; i < 4; i++) { \
                float h = acc[i] - xv[i] * wd + bs; \
                h = fmaxf(h, 0.0f); \
                hbw[(kc * 4 + i) * 32 + f * 16 + r] = f2bf(h); \
            } \
        } \
        __builtin_amdgcn_wave_barrier(); \
        short8 ah = *(const short8*)(hbw + r * 32 + kc * 8); \
        f32x4 zt0 = {0.f, 0.f, 0.f, 0.f}, zt1 = {0.f, 0.f, 0.f, 0.f}; \
        zt0 = __builtin_amdgcn_mfma_f32_16x16x32_bf16(wb0, ah, zt0, 0, 0, 0); \
        zt1 = __builtin_amdgcn_mfma_f32_16x16x32_bf16(wb1, ah, zt1, 0, 0, 0); \
        float p = 0.f; \
        _Pragma("unroll") for (int i = 0; i < 4; i++) { \
            p = fmaf(fmaxf(zt0[i] + b0i[i], 0.0f), w2a[i], p); \
            p = fmaf(fmaxf(zt1[i] + b1i[i], 0.0f), w2b[i], p); \
        } \
        p += __shfl_xor(p, 16, 64); \
        p += __shfl_xor(p, 32, 64); \
        if (lane < 16) flw[lane * 65 + g] = p + bn2; \
    } \
    __builtin_amdgcn_wave_barrier(); \
    _Pragma("unroll") for (int q = 0; q < 16; q++) \
        feat_out[(size_t)(bt0 + q) * NV + lane] = flw[q * 65 + lane]; \
}

// ---------------- K_mid: GRU (0..63) | ctxMLP (64..191) | feat half A (192..447) | LSTM gates (448..959) ----------------
__global__ __launch_bounds__(256, 1) void k_mid(
    const float* __restrict__ gg_t, const int* __restrict__ lengths,
    const unsigned short* __restrict__ whhg_h, const float* __restrict__ bhh,
    float* __restrict__ ctx,
    const float* __restrict__ stats, const float* __restrict__ Wc1,
    const float* __restrict__ bc1, const float* __restrict__ Wc2,
    const float* __restrict__ bc2,
    const float* __restrict__ xcomp, const float* __restrict__ masks,
    const unsigned short* __restrict__ wbf,
    const float* __restrict__ wdiag, const float* __restrict__ bfeat,
    const float* __restrict__ Wnl1, const float* __restrict__ bnl1,
    const float* __restrict__ Wnl2, const float* __restrict__ bnl2,
    float* __restrict__ feat_out,
    const unsigned short* __restrict__ wgf, const unsigned short* __restrict__ wgb,
    float* __restrict__ gf, float* __restrict__ gb) {
    // GRU LDS
    __shared__ __align__(16) unsigned short hsg[3][2][32];
    __shared__ __align__(16) float gexg[2][2][32][5];
    // ctxMLP LDS
    __shared__ __align__(16) float ss[193];
    __shared__ float h1[64];
    // feat LDS
    __shared__ __align__(16) unsigned short hbs[4][16 * 32];
    __shared__ __align__(16) float ldsx[4][64 * 16];
    __shared__ __align__(16) float fls[4][16 * 65];

    int bx = blockIdx.x;
    int tid = threadIdx.x;

    if (bx < 64) {
        // ================= GRU =================
        int b0 = bx * 2;
        int g = tid >> 6;
        int lane = tid & 63;
        int s = lane >> 5, n = lane & 31;
        if (g == 3) {
            for (int t = 0; t < NT; t++) block_sync_lds();
            return;
        }
        int b = b0 + s;
        const __half2 zh2 = __float2half2_rn(0.f);
        int4 w4[4];
        {
            const int4* wp = (const int4*)(whhg_h + (size_t)(g * 32 + n) * 32);
            #pragma unroll
            for (int q = 0; q < 4; q++) w4[q] = wp[q];
        }
        const __half2* w2 = (const __half2*)w4;
        float bh = bhh[g * 32 + n];
        int len = lengths[b];
        float hprev = 0.f, hn = 0.f;
        hsg[g][s][n] = f2h(0.f);
        const float* gbase = gg_t + (size_t)b * NT * 96;
        #define GGIDX(T) ((size_t)(T) * 96 + g * 32 + n)
        float gi0 = gbase[GGIDX(0)];
        float gi1 = gbase[GGIDX(1)];
        float gi2 = gbase[GGIDX(2)];
        float gi3 = gbase[GGIDX(3)];
        wave_lds_fence();
        for (int t = 0; t < 252; t += 4) {
            GRU_STEP(t, gi0)
            gi0 = gbase[GGIDX(t + 4)];
            GRU_STEP(t + 1, gi1)
            gi1 = gbase[GGIDX(t + 5)];
            GRU_STEP(t + 2, gi2)
            gi2 = gbase[GGIDX(t + 6)];
            GRU_STEP(t + 3, gi3)
            gi3 = gbase[GGIDX(t + 7)];
        }
        GRU_STEP(252, gi0)
        GRU_STEP(253, gi1)
        GRU_STEP(254, gi2)
        GRU_STEP(255, gi3)
        #undef GGIDX
        if (g == 0) ctx[(b0 + s) * 64 + 32 + n] = hn;
    } else if (bx < 192) {
        // ================= ctx MLP =================
        if (tid >= 64) return;
        int b = bx - 64;
        ss[tid] = stats[b * 256 + tid];
        ss[64 + tid] = stats[b * 256 + 64 + tid];
        ss[128 + tid] = stats[b * 256 + 128 + tid];
        if (tid == 0) ss[192] = stats[b * 256 + 192];
        wave_lds_fence();
        float acc = bc1[tid];
        const float* w = Wc1 + (size_t)tid * 193;
        for (int k = 0; k < 193; k++) acc = fmaf(w[k], ss[k], acc);
        h1[tid] = fmaxf(acc, 0.f);
        wave_lds_fence();
        if (tid < 32) {
            float a = bc2[tid];
            const float* w2 = Wc2 + tid * 64;
            for (int k = 0; k < 64; k++) a = fmaf(w2[k], h1[k], a);
            ctx[b * 64 + tid] = a;
        }
    } else if (bx < 448) {
        // ================= feat MLP half A =================
        int wave = tid >> 6; int lane = tid & 63;
        FEAT_BODY((bx - 192) * 64 + wave * 16)
    } else {
        // ================= LSTM input-gate GEMM (gf, gb) =================
        int wave = tid >> 6, lane = tid & 63;
        int bt0 = (bx - 448) * 64 + wave * 16;
        int r = lane & 15, kc = lane >> 4;
        const float* xr = xcomp + (size_t)(bt0 + r) * NV + kc * 8;
        const float* mr = masks + (size_t)(bt0 + r) * NV + kc * 8;
        short8 af0 = pack8(*(const float4*)(xr), *(const float4*)(xr + 4));
        short8 af1 = pack8(*(const float4*)(xr + 32), *(const float4*)(xr + 36));
        short8 af2 = pack8(*(const float4*)(mr), *(const float4*)(mr + 4));
        short8 af3 = pack8(*(const float4*)(mr + 32), *(const float4*)(mr + 36));
        #pragma unroll 4
        for (int nt = 0; nt < 16; nt++) {
            const unsigned short* w = wgf + (size_t)(nt * 16 + r) * 128 + kc * 8;
            f32x4 acc = {0.f, 0.f, 0.f, 0.f};
            acc = __builtin_amdgcn_mfma_f32_16x16x32_bf16(af0, *(const short8*)(w), acc, 0, 0, 0);
            acc = __builtin_amdgcn_mfma_f32_16x16x32_bf16(af1, *(const short8*)(w + 32), acc, 0, 0, 0);
            acc = __builtin_amdgcn_mfma_f32_16x16x32_bf16(af2, *(const short8*)(w + 64), acc, 0, 0, 0);
            acc = __builtin_amdgcn_mfma_f32_16x16x32_bf16(af3, *(const short8*)(w + 96), acc, 0, 0, 0);
            int col = nt * 16 + r, g = col >> 6, n = col & 63;
            #pragma unroll
            for (int i = 0; i < 4; i++)
                gf[((size_t)(bt0 + kc * 4 + i) * 64 + n) * 4 + g] = acc[i];
        }
        #pragma unroll 4
        for (int nt = 0; nt < 16; nt++) {
            const unsigned short* w = wgb + (size_t)(nt * 16 + r) * 128 + kc * 8;
            f32x4 acc = {0.f, 0.f, 0.f, 0.f};
            acc = __builtin_amdgcn_mfma_f32_16x16x32_bf16(af0, *(const short8*)(w), acc, 0, 0, 0);
            acc = __builtin_amdgcn_mfma_f32_16x16x32_bf16(af1, *(const short8*)(w + 32), acc, 0, 0, 0);
            acc = __builtin_amdgcn_mfma_f32_16x16x32_bf16(af2, *(const short8*)(w + 64), acc, 0, 0, 0);
            acc = __builtin_amdgcn_mfma_f32_16x16x32_bf16(af3, *(const short8*)(w + 96), acc, 0, 0, 0);
            int col = nt * 16 + r, g = col >> 6, n = col & 63;
            #pragma unroll
            for (int i = 0; i < 4; i++)
                gb[((size_t)(bt0 + kc * 4 + i) * 64 + n) * 4 + g] = acc[i];
        }
    }
}

// ---------------- K6: barrier-free LSTM (blocks 0..63, 1 wave = 1 recurrence) + feat half B (64..319) ----------------
#define LSTM_STEP2(S, GI) { \
    int4 raw_[8]; \
    const int4* hp_ = (const int4*)hsw[wid]; \
    _Pragma("unroll") for (int q = 0; q < 8; q++) raw_[q] = hp_[q]; \
    const __half2* hhv_ = (const __half2*)raw_; \
    float dd_[4]; \
    _Pragma("unroll") for (int g = 0; g < 4; g++) { \
        __half2 a0_ = zh2, a1_ = zh2, a2_ = zh2, a3_ = zh2; \
        _Pragma("unroll") for (int q = 0; q < 32; q += 4) { \
            a0_ = __hfma2(w2[g * 32 + q],     hhv_[q],     a0_); \
            a1_ = __hfma2(w2[g * 32 + q + 1], hhv_[q + 1], a1_); \
            a2_ = __hfma2(w2[g * 32 + q + 2], hhv_[q + 2], a2_); \
            a3_ = __hfma2(w2[g * 32 + q + 3], hhv_[q + 3], a3_); } \
        __half2 sA_ = __hadd2(__hadd2(a0_, a1_), __hadd2(a2_, a3_)); \
        dd_[g] = __low2float(sA_) + __high2float(sA_); \
    } \
    float ii_ = fsigm(GI.x + ctg0 + dd_[0]); \
    float ff_ = fsigm(GI.y + ctg1 + dd_[1]); \
    float gv_ = ftanh(GI.z + ctg2 + dd_[2]); \
    float oo_ = fsigm(GI.w + ctg3 + dd_[3]); \
    c = ff_ * c + ii_ * gv_; \
    float hv_ = oo_ * ftanh(c); \
    int tout_ = dir ? (NT - 2 - (S)) : ((S) + 1); \
    hall[((size_t)b * NT + tout_) * NV + n] = hv_; \
    hsw[wid][n] = f2h(hv_); \
    wave_lds_fence(); \
}

__global__ __launch_bounds__(256, 1) void k_lstm(
    const float* __restrict__ gf, const float* __restrict__ gb,
    const float* __restrict__ ctx,
    const unsigned short* __restrict__ whhf_h, const unsigned short* __restrict__ whhb_h,
    const float* __restrict__ Wihf, const float* __restrict__ Wihb,
    const float* __restrict__ bihf, const float* __restrict__ bhhf,
    const float* __restrict__ bihb, const float* __restrict__ bhhb,
    const float* __restrict__ Wini, const float* __restrict__ bini,
    float* __restrict__ out0, float* __restrict__ out1,
    const float* __restrict__ xcomp, const unsigned short* __restrict__ wbf,
    const float* __restrict__ wdiag, const float* __restrict__ bfeat,
    const float* __restrict__ Wnl1, const float* __restrict__ bnl1,
    const float* __restrict__ Wnl2, const float* __restrict__ bnl2,
    float* __restrict__ feat_out) {
    // LSTM LDS (per-wave private)
    __shared__ __align__(16) unsigned short hsw[4][64];
    __shared__ __align__(16) float sctxw[4][64];
    // feat LDS
    __shared__ __align__(16) unsigned short hbs[4][16 * 32];
    __shared__ __align__(16) float ldsx[4][64 * 16];
    __shared__ __align__(16) float fls[4][16 * 65];

    int bx = blockIdx.x;
    int tid = threadIdx.x;

    if (bx >= 64) {
        // ================= feat MLP half B =================
        int wave = tid >> 6; int lane = tid & 63;
        FEAT_BODY((bx - 64) * 64 + 16384 + wave * 16)
        return;
    }

    // ================= barrier-free LSTM: one wave per recurrence =================
    int wid = tid >> 6;
    int n = tid & 63;
    int rid = bx * 4 + wid;              // 0..255
    int dir = rid >> 7; int b = rid & 127;
    const float* gates = dir ? gb : gf;
    const unsigned short* wsrc = dir ? whhb_h : whhf_h;
    float* hall = dir ? out1 : out0;
    const __half2 zh2 = __float2half2_rn(0.f);
    // all 4 gate weight rows for unit n (4 × 64 f16 = 32 int4)
    int4 w4[32];
    #pragma unroll
    for (int g = 0; g < 4; g++) {
        const int4* wp = (const int4*)(wsrc + (size_t)(g * 64 + n) * 64);
        #pragma unroll
        for (int q = 0; q < 8; q++) w4[g * 8 + q] = wp[q];
    }
    const __half2* w2 = (const __half2*)w4;
    // ---- prologue: ctx to LDS, cterm (4 per lane), hinit ----
    sctxw[wid][n] = ctx[b * 64 + n];
    wave_lds_fence();
    float ctg0, ctg1, ctg2, ctg3;
    {
        const float* base_ih = dir ? Wihb : Wihf;
        const float4* c4 = (const float4*)sctxw[wid];
        const float4* wc0 = (const float4*)(base_ih + (size_t)(0 * 64 + n) * 192 + 128);
        const float4* wc1 = (const float4*)(base_ih + (size_t)(1 * 64 + n) * 192 + 128);
        const float4* wc2 = (const float4*)(base_ih + (size_t)(2 * 64 + n) * 192 + 128);
        const float4* wc3 = (const float4*)(base_ih + (size_t)(3 * 64 + n) * 192 + 128);
        float4 a0 = {0,0,0,0}, a1 = {0,0,0,0}, a2 = {0,0,0,0}, a3 = {0,0,0,0};
        #pragma unroll
        for (int q = 0; q < 16; q++) {
            float4 cv = c4[q];
            dot4(a0, wc0[q], cv); dot4(a1, wc1[q], cv);
            dot4(a2, wc2[q], cv); dot4(a3, wc3[q], cv);
        }
        const float* bih = dir ? bihb : bihf;
        const float* bhh2 = dir ? bhhb : bhhf;
        ctg0 = bih[n]       + bhh2[n]       + a0.x + a0.y + a0.z + a0.w;
        ctg1 = bih[64 + n]  + bhh2[64 + n]  + a1.x + a1.y + a1.z + a1.w;
        ctg2 = bih[128 + n] + bhh2[128 + n] + a2.x + a2.y + a2.z + a2.w;
        ctg3 = bih[192 + n] + bhh2[192 + n] + a3.x + a3.y + a3.z + a3.w;
    }
    float c;
    {
        const float4* wi = (const float4*)(Wini + (size_t)(dir * 64 + n) * 64);
        const float4* c4 = (const float4*)sctxw[wid];
        float4 a = {0, 0, 0, 0};
        #pragma unroll
        for (int q = 0; q < 16; q++) dot4(a, wi[q], c4[q]);
        float h0 = bini[dir * 64 + n] + a.x + a.y + a.z + a.w;
        c = ftanh(h0);
        hsw[wid][n] = f2h(h0);
        int t0 = dir ? (NT - 1) : 0;
        hall[((size_t)b * NT + t0) * NV + n] = h0;
    }
    wave_lds_fence();
    size_t gbase = (size_t)b * NT * 256 + (size_t)n * 4;
    #define GP(S) (*(const float4*)(gates + gbase + (size_t)(dir ? (NT - 1 - (S)) : (S)) * 256))
    float4 gi0 = GP(0);
    float4 gi1 = GP(1);
    float4 gi2 = GP(2);
    float4 gi3 = GP(3);
    for (int sx = 0; sx < 252; sx += 4) {
        LSTM_STEP2(sx, gi0)
        gi0 = GP(sx + 4);
        LSTM_STEP2(sx + 1, gi1)
        gi1 = GP(sx + 5);
        LSTM_STEP2(sx + 2, gi2)
        gi2 = GP(sx + 6);
        LSTM_STEP2(sx + 3, gi3)
        gi3 = GP(sx + 7);
    }
    LSTM_STEP2(252, gi0)
    LSTM_STEP2(253, gi1)
    LSTM_STEP2(254, gi2)
    #undef GP
}

// ---------------- K_post: fused rnn_imp GEMM + beta GEMM + fusion + scaling ----------------
__global__ __launch_bounds__(256) void k_post(
    const unsigned short* __restrict__ gam, const float* __restrict__ masks,
    const unsigned short* __restrict__ wri_bf, const unsigned short* __restrict__ wfu_bf,
    const float* __restrict__ bri, const float* __restrict__ bfu,
    const float* __restrict__ mmn_ws, const float* __restrict__ minv,
    float* out0, float* out1, float* out2) {
    int wave = threadIdx.x >> 6, lane = threadIdx.x & 63;
    int bt0 = blockIdx.x * 64 + wave * 16;
    int r = lane & 15, kc = lane >> 4;
    int b = bt0 >> 8;
    const float* h0r = out0 + (size_t)(bt0 + r) * NV + kc * 8;
    const float* h1r = out1 + (size_t)(bt0 + r) * NV + kc * 8;
    const unsigned short* gr = gam + (size_t)(bt0 + r) * NV + kc * 8;
    const float* mr  = masks + (size_t)(bt0 + r) * NV + kc * 8;
    short8 A0 = pack8(*(const float4*)(h0r), *(const float4*)(h0r + 4));
    short8 A1 = pack8(*(const float4*)(h0r + 32), *(const float4*)(h0r + 36));
    short8 A2 = pack8(*(const float4*)(h1r), *(const float4*)(h1r + 4));
    short8 A3 = pack8(*(const float4*)(h1r + 32), *(const float4*)(h1r + 36));
    short8 G0 = *(const short8*)(gr);
    short8 G1 = *(const short8*)(gr + 32);
    short8 M0 = pack8(*(const float4*)(mr), *(const float4*)(mr + 4));
    short8 M1 = pack8(*(const float4*)(mr + 32), *(const float4*)(mr + 36));
    #pragma unroll
    for (int nt = 0; nt < 4; nt++) {
        int n = nt * 16 + r;
        const unsigned short* wr = wri_bf + (size_t)n * 128 + kc * 8;
        const unsigned short* wf = wfu_bf + (size_t)n * 128 + kc * 8;
        float bi = bri[n], bf_ = bfu[n];
        f32x4 racc = {bi, bi, bi, bi};
        f32x4 bacc = {bf_, bf_, bf_, bf_};
        racc = __builtin_amdgcn_mfma_f32_16x16x32_bf16(A0, *(const short8*)(wr), racc, 0, 0, 0);
        racc = __builtin_amdgcn_mfma_f32_16x16x32_bf16(A1, *(const short8*)(wr + 32), racc, 0, 0, 0);
        racc = __builtin_amdgcn_mfma_f32_16x16x32_bf16(A2, *(const short8*)(wr + 64), racc, 0, 0, 0);
        racc = __builtin_amdgcn_mfma_f32_16x16x32_bf16(A3, *(const short8*)(wr + 96), racc, 0, 0, 0);
        bacc = __builtin_amdgcn_mfma_f32_16x16x32_bf16(G0, *(const short8*)(wf), bacc, 0, 0, 0);
        bacc = __builtin_amdgcn_mfma_f32_16x16x32_bf16(G1, *(const short8*)(wf + 32), bacc, 0, 0, 0);
        bacc = __builtin_amdgcn_mfma_f32_16x16x32_bf16(M0, *(const short8*)(wf + 64), bacc, 0, 0, 0);
        bacc = __builtin_amdgcn_mfma_f32_16x16x32_bf16(M1, *(const short8*)(wf + 96), bacc, 0, 0, 0);
        float mm = mmn_ws[b * NV + n], mn = minv[b * NV + n];
        #pragma unroll
        for (int i = 0; i < 4; i++) {
            int row = bt0 + kc * 4 + i;
            size_t idx = (size_t)row * NV + n;
            float rn = racc[i];
            float beta = fsigm(bacc[i]);
            float ft = out2[idx];
            float fin = beta * ft + (1.0f - beta) * rn;
            out0[idx] = fmaf(rn, mm, mn);
            out1[idx] = fmaf(ft, mm, mn);
            out2[idx] = fmaf(fin, mm, mn);
        }
    }
}

extern "C" void kernel_launch(void* const* d_in, const int* in_sizes, int n_in,
                              void* d_out, int out_size, void* d_ws, size_t ws_size,
                              hipStream_t stream) {
    const int*   lengths  = (const int*)d_in[0];
    const float* values   = (const float*)d_in[1];
    const float* masks    = (const float*)d_in[2];
    const float* deltas   = (const float*)d_in[3];
    const float* min_vals = (const float*)d_in[4];
    const float* max_vals = (const float*)d_in[5];
    const float* W_decay  = (const float*)d_in[6];
    const float* b_decay  = (const float*)d_in[7];
    const float* W_feat   = (const float*)d_in[8];
    const float* b_feat   = (const float*)d_in[9];
    const float* W_nl1    = (const float*)d_in[10];
    const float* b_nl1    = (const float*)d_in[11];
    const float* W_nl2    = (const float*)d_in[12];
    const float* b_nl2    = (const float*)d_in[13];
    const float* Wc1      = (const float*)d_in[14];
    const float* bc1      = (const float*)d_in[15];
    const float* Wc2      = (const float*)d_in[16];
    const float* bc2      = (const float*)d_in[17];
    const float* W_ih_g   = (const float*)d_in[18];
    const float* W_hh_g   = (const float*)d_in[19];
    const float* b_ih_g   = (const float*)d_in[20];
    const float* b_hh_g   = (const float*)d_in[21];
    const float* W_init   = (const float*)d_in[22];
    const float* b_init   = (const float*)d_in[23];
    const float* W_ih_f   = (const float*)d_in[24];
    const float* W_hh_f   = (const float*)d_in[25];
    const float* b_ih_f   = (const float*)d_in[26];
    const float* b_hh_f   = (const float*)d_in[27];
    const float* W_ih_b   = (const float*)d_in[28];
    const float* W_hh_b   = (const float*)d_in[29];
    const float* b_ih_b   = (const float*)d_in[30];
    const float* b_hh_b   = (const float*)d_in[31];
    const float* W_ri     = (const float*)d_in[32];
    const float* b_ri     = (const float*)d_in[33];
    const float* W_fu     = (const float*)d_in[34];
    const float* b_fu     = (const float*)d_in[35];

    float* ws = (float*)d_ws;
    float* xcomp  = ws;                     // 2097152
    unsigned short* gam = (unsigned short*)(ws + 2097152);  // 2097152 u16 (4 MB)
    unsigned short* wri_bf = (unsigned short*)(ws + 4194304); // 8192 u16
    unsigned short* wfu_bf = (unsigned short*)(ws + 4198400); // 8192 u16
    float* stats  = ws + 6291456;           // 32768
    float* mmn    = ws + 6324224;           // 8192
    float* nmeans = ws + 6332416;           // 8192
    float* ctx    = ws + 6340608;           // 8192
    unsigned short* wbf = (unsigned short*)(ws + 6365184);  // 131072 u16
    float* wdiag  = ws + 6430720;           // 2048
    unsigned short* wgf = (unsigned short*)(ws + 6432768);  // 32768 u16
    unsigned short* wgb = (unsigned short*)(ws + 6449152);  // 32768 u16
    unsigned short* wgg = (unsigned short*)(ws + 6465536);  // 12288 u16
    unsigned short* whhf_h = (unsigned short*)(ws + 6471680); // 16384 u16
    unsigned short* whhb_h = (unsigned short*)(ws + 6479872); // 16384 u16
    unsigned short* whhg_h = (unsigned short*)(ws + 6488064); // 3072 u16
    float* gates_f = ws + 6555136;          // 8388608
    float* gates_b = ws + 14943744;         // 8388608
    float* gates_g = ws + 23332352;         // 3145728  (end ≈ 106 MB)

    float* out0 = (float*)d_out;
    float* out1 = out0 + NBTV;
    float* out2 = out0 + 2 * NBTV;

    k_prep<<<512, 256, 0, stream>>>(W_feat, W_ih_f, W_ih_b, W_ih_g, W_hh_f, W_hh_b, W_hh_g,
                                    W_ri, W_fu,
                                    wbf, wdiag, wgf, wgb, wgg, whhf_h, whhb_h, whhg_h,
                                    wri_bf, wfu_bf);
    k_fill<<<NB, 256, 0, stream>>>(lengths, values, masks, deltas, min_vals, max_vals,
                                   W_decay, b_decay, stats, mmn, nmeans, xcomp, gam,
                                   wgg, b_ih_g, gates_g);
    k_mid<<<960, 256, 0, stream>>>(gates_g, lengths, whhg_h, b_hh_g, ctx,
                                   stats, Wc1, bc1, Wc2, bc2,
                                   xcomp, masks, wbf, wdiag, b_feat, W_nl1, b_nl1, W_nl2, b_nl2, out2,
                                   wgf, wgb, gates_f, gates_b);
    k_lstm<<<320, 256, 0, stream>>>(gates_f, gates_b, ctx, whhf_h, whhb_h,
                                    W_ih_f, W_ih_b, b_ih_f, b_hh_f, b_ih_b, b_hh_b,
                                    W_init, b_init, out0, out1,
                                    xcomp, wbf, wdiag, b_feat, W_nl1, b_nl1, W_nl2, b_nl2, out2);
    k_post<<<NBT / 64, 256, 0, stream>>>(gam, masks, wri_bf, wfu_bf, b_ri, b_fu, mmn, min_vals,
                                         out0, out1, out2);
}

// Round 27
// 251.426 us; speedup vs baseline: 1.1887x; 1.1887x over previous
//
#include <hip/hip_runtime.h>
#include <hip/hip_fp16.h>

static constexpr int NB = 128;
static constexpr int NT = 256;
static constexpr int NV = 64;
static constexpr int NBT = NB * NT;       // 32768
static constexpr int NBTV = NBT * NV;     // 2097152

typedef __attribute__((ext_vector_type(8))) short short8;
typedef __attribute__((ext_vector_type(4))) float f32x4;
typedef __attribute__((ext_vector_type(4))) float fvec4;

__device__ __forceinline__ void wave_lds_fence() {
    __builtin_amdgcn_sched_barrier(0);
    asm volatile("s_waitcnt lgkmcnt(0)" ::: "memory");
    __builtin_amdgcn_sched_barrier(0);
}

// cross-wave barrier with LDS visibility, WITHOUT vmcnt drain.
__device__ __forceinline__ void block_sync_lds() {
    __builtin_amdgcn_sched_barrier(0);
    asm volatile("s_waitcnt lgkmcnt(0)" ::: "memory");
    __builtin_amdgcn_s_barrier();
    asm volatile("" ::: "memory");
    __builtin_amdgcn_sched_barrier(0);
}

__device__ __forceinline__ unsigned short f2bf(float x) {
    unsigned int u = __float_as_uint(x);
    return (unsigned short)((u + 0x7FFFu + ((u >> 16) & 1u)) >> 16);
}
__device__ __forceinline__ float bf2f(unsigned short b) {
    return __uint_as_float(((unsigned int)b) << 16);
}
__device__ __forceinline__ unsigned short f2h(float x) {
    union { _Float16 h; unsigned short u; } c; c.h = (_Float16)x; return c.u;
}
__device__ __forceinline__ float fsigm(float x) {
    return __builtin_amdgcn_rcpf(1.0f + __expf(-x));
}
__device__ __forceinline__ float ftanh(float x) {
    return 1.0f - 2.0f * __builtin_amdgcn_rcpf(1.0f + __expf(2.0f * x));
}

__device__ __forceinline__ short8 pack8(float4 a, float4 b) {
    short8 r;
    r[0] = (short)f2bf(a.x); r[1] = (short)f2bf(a.y); r[2] = (short)f2bf(a.z); r[3] = (short)f2bf(a.w);
    r[4] = (short)f2bf(b.x); r[5] = (short)f2bf(b.y); r[6] = (short)f2bf(b.z); r[7] = (short)f2bf(b.w);
    return r;
}

__device__ __forceinline__ void dot4(float4& acc, const float4 wv, const float4 xv) {
    acc.x = fmaf(wv.x, xv.x, acc.x);
    acc.y = fmaf(wv.y, xv.y, acc.y);
    acc.z = fmaf(wv.z, xv.z, acc.z);
    acc.w = fmaf(wv.w, xv.w, acc.w);
}

// ---------------- K_prep: weight conversions only (512 blocks) ----------------
__global__ __launch_bounds__(256) void k_prep(
    const float* __restrict__ Wf, const float* __restrict__ Wihf,
    const float* __restrict__ Wihb, const float* __restrict__ Wihg,
    const float* __restrict__ Whhf, const float* __restrict__ Whhb,
    const float* __restrict__ Whhg, const float* __restrict__ Wri,
    const float* __restrict__ Wfu,
    unsigned short* __restrict__ wbf, float* __restrict__ wdiag,
    unsigned short* __restrict__ wgf, unsigned short* __restrict__ wgb,
    unsigned short* __restrict__ wgg,
    unsigned short* __restrict__ whhf_h, unsigned short* __restrict__ whhb_h,
    unsigned short* __restrict__ whhg_h,
    unsigned short* __restrict__ wri_bf, unsigned short* __restrict__ wfu_bf) {
    int i = blockIdx.x * 256 + threadIdx.x;
    if (i < NV * 32 * NV) wbf[i] = f2bf(Wf[i]);
    if (i < 2048) wdiag[i] = bf2f(f2bf(Wf[i * 64 + (i >> 5)]));
    if (i < 32768) {
        int n = i >> 7, k = i & 127;
        wgf[i] = f2bf(Wihf[n * 192 + k]);
        wgb[i] = f2bf(Wihb[n * 192 + k]);
    }
    if (i < 12288) wgg[i] = f2bf(Wihg[i]);
    if (i < 16384) { whhf_h[i] = f2h(Whhf[i]); whhb_h[i] = f2h(Whhb[i]); }
    if (i < 3072) whhg_h[i] = f2h(Whhg[i]);
    if (i < 8192) { wri_bf[i] = f2bf(Wri[i]); wfu_bf[i] = f2bf(Wfu[i]); }
}

// ---------------- K2: stats + forward-fill + decay + x_complete + GRU gate GEMM ----------------
__global__ __launch_bounds__(256) void k_fill(
    const int* __restrict__ lengths,
    const float* __restrict__ values, const float* __restrict__ masks,
    const float* __restrict__ deltas, const float* __restrict__ minv,
    const float* __restrict__ maxv,
    const float* __restrict__ Wd, const float* __restrict__ bd,
    float* __restrict__ stats,
    float* __restrict__ mmn_ws, float* __restrict__ nmeans_ws,
    float* __restrict__ xcomp, unsigned short* __restrict__ gam,
    const unsigned short* __restrict__ wgg, const float* __restrict__ bihg,
    float* __restrict__ gg) {
    int b = blockIdx.x; int tid = threadIdx.x;
    int v = tid & 63; int tc = tid >> 6;
    float mn = minv[b * NV + v];
    size_t base = (size_t)b * NT * NV + v;
    __shared__ float red[3][4][64];
    __shared__ float lastv[4][64];
    __shared__ int hasf[4][64];
    __shared__ float nv0s[64];
    __shared__ float smm[64], snm[64];
    __shared__ __align__(16) unsigned short sxc[256][64];   // bf16 xcomp tile (32 KB)
    int t0 = tc * 64;
    float sv = 0.f, sq = 0.f, sm = 0.f;
    float last = 0.f; int has = 0;
    for (int t = t0; t < t0 + 64; t++) {
        float val = values[base + (size_t)t * NV];
        float m = masks[base + (size_t)t * NV];
        sv += val; sq += val * val; sm += m;
        if (m != 0.f) { last = val; has = 1; }
        if (tc == 0 && t == 0) nv0s[v] = val;
    }
    red[0][tc][v] = sv; red[1][tc][v] = sq; red[2][tc][v] = sm;
    lastv[tc][v] = last; hasf[tc][v] = has;
    __syncthreads();
    if (tc == 0) {
        sv = red[0][0][v] + red[0][1][v] + red[0][2][v] + red[0][3][v];
        sq = red[1][0][v] + red[1][1][v] + red[1][2][v] + red[1][3][v];
        sm = red[2][0][v] + red[2][1][v] + red[2][2][v] + red[2][3][v];
        float mean = sv / sm;
        float var = (sq - 2.0f * mean * sv + (float)NT * mean * mean) / (sm - 1.0f);
        var = fmaxf(var, 0.0f);
        float sd = sqrtf(var);
        float lf = (float)lengths[b];
        float miss = 1.0f - sm / lf;
        float mx = maxv[b * NV + v];
        float mm = fmaxf(mx - mn, 1e-8f);
        float* st = stats + b * 256;
        if (v == 0) st[0] = lf;
        st[1 + v] = mean; st[65 + v] = sd; st[129 + v] = miss;
        float nmean = (mean - mn) / mm;
        mmn_ws[b * NV + v] = mm;
        nmeans_ws[b * NV + v] = nmean;
        smm[v] = mm; snm[v] = nmean;
    }
    __syncthreads();
    float mm = smm[v];
    float nmean = snm[v];
    float wd = Wd[v * NV + v], bdv = bd[v];
    float xp = (nv0s[v] - mn) / mm;
    for (int q = tc - 1; q >= 0; q--) {
        if (hasf[q][v]) { xp = (lastv[q][v] - mn) / mm; break; }
    }
    for (int t = t0; t < t0 + 64; t++) {
        size_t i = base + (size_t)t * NV;
        float val = values[i], m = masks[i], d = deltas[i];
        float nv = (val - mn) / mm;
        float g = expf(-fmaxf(fmaf(d, wd, bdv), 0.0f));
        float xd = g * xp + (1.0f - g) * nmean;
        float xc = m * nv + (1.0f - m) * xd;
        xcomp[i] = xc; gam[i] = f2bf(g);
        sxc[t][v] = f2bf(xc);
        xp = (m != 0.f) ? nv : xp;
    }
    __syncthreads();
    // ---- GRU input-gate GEMM for this sample (4 tiles per wave) ----
    int lane = tid & 63;
    int r = lane & 15, kc = lane >> 4;
    for (int tile = 0; tile < 4; tile++) {
        int trow = (tc * 4 + tile) * 16;
        int bt0 = b * NT + trow;
        short8 af0 = *(const short8*)&sxc[trow + r][kc * 8];
        short8 af1 = *(const short8*)&sxc[trow + r][32 + kc * 8];
        const float* mr = masks + ((size_t)bt0 + r) * NV + kc * 8;
        short8 af2 = pack8(*(const float4*)(mr), *(const float4*)(mr + 4));
        short8 af3 = pack8(*(const float4*)(mr + 32), *(const float4*)(mr + 36));
        #pragma unroll 3
        for (int nt = 0; nt < 6; nt++) {
            const unsigned short* w = wgg + (size_t)(nt * 16 + r) * 128 + kc * 8;
            float bias = bihg[nt * 16 + r];
            f32x4 acc = {bias, bias, bias, bias};
            acc = __builtin_amdgcn_mfma_f32_16x16x32_bf16(af0, *(const short8*)(w), acc, 0, 0, 0);
            acc = __builtin_amdgcn_mfma_f32_16x16x32_bf16(af1, *(const short8*)(w + 32), acc, 0, 0, 0);
            acc = __builtin_amdgcn_mfma_f32_16x16x32_bf16(af2, *(const short8*)(w + 64), acc, 0, 0, 0);
            acc = __builtin_amdgcn_mfma_f32_16x16x32_bf16(af3, *(const short8*)(w + 96), acc, 0, 0, 0);
            #pragma unroll
            for (int i = 0; i < 4; i++)
                gg[(size_t)(bt0 + kc * 4 + i) * 96 + nt * 16 + r] = acc[i];
        }
    }
}

// ---------------- GRU step ----------------
#define GRU_STEP(T, GIN) { \
    const int t_ = (T); const int p_ = t_ & 1; \
    int4 raw_[4]; \
    const int4* hp_ = (const int4*)hsg[g][s]; \
    _Pragma("unroll") for (int q = 0; q < 4; q++) raw_[q] = hp_[q]; \
    const __half2* hhv_ = (const __half2*)raw_; \
    __half2 a0_ = zh2, a1_ = zh2, a2_ = zh2, a3_ = zh2; \
    _Pragma("unroll") for (int q = 0; q < 16; q += 4) { \
        a0_ = __hfma2(w2[q],     hhv_[q],     a0_); \
        a1_ = __hfma2(w2[q + 1], hhv_[q + 1], a1_); \
        a2_ = __hfma2(w2[q + 2], hhv_[q + 2], a2_); \
        a3_ = __hfma2(w2[q + 3], hhv_[q + 3], a3_); } \
    __half2 sA_ = __hadd2(__hadd2(a0_, a1_), __hadd2(a2_, a3_)); \
    float d_ = __low2float(sA_) + __high2float(sA_); \
    if (g < 2) { \
        gexg[p_][s][n][g] = GIN + bh + d_; \
    } else { \
        gexg[p_][s][n][2] = bh + d_; \
        gexg[p_][s][n][3] = GIN; \
    } \
    block_sync_lds(); \
    float qx_ = gexg[p_][s][n][0], qy_ = gexg[p_][s][n][1]; \
    float qz_ = gexg[p_][s][n][2], qw_ = gexg[p_][s][n][3]; \
    float rr_ = fsigm(qx_); \
    float zz_ = fsigm(qy_); \
    float nn_ = ftanh(qw_ + rr_ * qz_); \
    float h_ = (1.f - zz_) * nn_ + zz_ * hprev; \
    hprev = h_; \
    if (t_ < len) hn = h_; \
    hsg[g][s][n] = f2h(h_); \
    wave_lds_fence(); \
}

// feat MLP body, per-wave independent
#define FEAT_BODY(BT0) { \
    int bt0 = (BT0); \
    int r = lane & 15, kc = lane >> 4; \
    unsigned short* hbw = hbs[wave]; \
    float* lx = ldsx[wave]; \
    float* flw = fls[wave]; \
    short8 a0, a1; \
    { \
        const float* xr = xcomp + (size_t)(bt0 + r) * NV + kc * 8; \
        a0 = pack8(*(const float4*)(xr), *(const float4*)(xr + 4)); \
        a1 = pack8(*(const float4*)(xr + 32), *(const float4*)(xr + 36)); \
    } \
    { \
        int gc0 = kc * 16; \
        const float* xr2 = xcomp + (size_t)(bt0 + r) * NV + gc0; \
        _Pragma("unroll") for (int e = 0; e < 16; e += 4) { \
            float4 p = *(const float4*)(xr2 + e); \
            lx[(gc0 + e + 0) * 16 + r] = bf2f(f2bf(p.x)); \
            lx[(gc0 + e + 1) * 16 + r] = bf2f(f2bf(p.y)); \
            lx[(gc0 + e + 2) * 16 + r] = bf2f(f2bf(p.z)); \
            lx[(gc0 + e + 3) * 16 + r] = bf2f(f2bf(p.w)); \
        } \
    } \
    short8 wb0, wb1; \
    { \
        const float* w = Wnl1 + r * 32 + kc * 8; \
        wb0 = pack8(*(const float4*)w, *(const float4*)(w + 4)); \
        const float* w2p = Wnl1 + (16 + r) * 32 + kc * 8; \
        wb1 = pack8(*(const float4*)w2p, *(const float4*)(w2p + 4)); \
    } \
    float b0i[4], b1i[4], w2a[4], w2b[4]; \
    _Pragma("unroll") for (int i = 0; i < 4; i++) { \
        b0i[i] = bnl1[kc * 4 + i]; \
        b1i[i] = bnl1[16 + kc * 4 + i]; \
        w2a[i] = Wnl2[kc * 4 + i]; \
        w2b[i] = Wnl2[16 + kc * 4 + i]; \
    } \
    float bn2 = bnl2[0]; \
    __builtin_amdgcn_wave_barrier(); \
    _Pragma("unroll 2") for (int g = 0; g < 64; g++) { \
        __builtin_amdgcn_wave_barrier(); \
        float xv[4]; \
        _Pragma("unroll") for (int i = 0; i < 4; i++) xv[i] = lx[g * 16 + kc * 4 + i]; \
        _Pragma("unroll") for (int f = 0; f < 2; f++) { \
            int n0 = g * 32 + f * 16; \
            const unsigned short* wrow = wbf + (size_t)(n0 + r) * 64; \
            short8 b0 = *(const short8*)(wrow + kc * 8); \
            short8 b1 = *(const short8*)(wrow + 32 + kc * 8); \
            f32x4 acc = {0.f, 0.f, 0.f, 0.f}; \
            acc = __builtin_amdgcn_mfma_f32_16x16x32_bf16(a0, b0, acc, 0, 0, 0); \
            acc = __builtin_amdgcn_mfma_f32_16x16x32_bf16(a1, b1, acc, 0, 0, 0); \
            int n = n0 + r; \
            float wd = wdiag[n], bs = bfeat[n]; \
            _Pragma("unroll") for (int i = 0; i < 4; i++) { \
                float h = acc[i] - xv[i] * wd + bs; \
                h = fmaxf(h, 0.0f); \
                hbw[(kc * 4 + i) * 32 + f * 16 + r] = f2bf(h); \
            } \
        } \
        __builtin_amdgcn_wave_barrier(); \
        short8 ah = *(const short8*)(hbw + r * 32 + kc * 8); \
        f32x4 zt0 = {0.f, 0.f, 0.f, 0.f}, zt1 = {0.f, 0.f, 0.f, 0.f}; \
        zt0 = __builtin_amdgcn_mfma_f32_16x16x32_bf16(wb0, ah, zt0, 0, 0, 0); \
        zt1 = __builtin_amdgcn_mfma_f32_16x16x32_bf16(wb1, ah, zt1, 0, 0, 0); \
        float p = 0.f; \
        _Pragma("unroll") for (int i = 0; i < 4; i++) { \
            p = fmaf(fmaxf(zt0[i] + b0i[i], 0.0f), w2a[i], p); \
            p = fmaf(fmaxf(zt1[i] + b1i[i], 0.0f), w2b[i], p); \
        } \
        p += __shfl_xor(p, 16, 64); \
        p += __shfl_xor(p, 32, 64); \
        if (lane < 16) flw[lane * 65 + g] = p + bn2; \
    } \
    __builtin_amdgcn_wave_barrier(); \
    _Pragma("unroll") for (int q = 0; q < 16; q++) \
        feat_out[(size_t)(bt0 + q) * NV + lane] = flw[q * 65 + lane]; \
}

// ---------------- K_mid: GRU (0..63) | ctxMLP (64..191) | feat half A (192..447) | LSTM gates (448..959) ----------------
__global__ __launch_bounds__(256, 1) void k_mid(
    const float* __restrict__ gg_t, const int* __restrict__ lengths,
    const unsigned short* __restrict__ whhg_h, const float* __restrict__ bhh,
    float* __restrict__ ctx,
    const float* __restrict__ stats, const float* __restrict__ Wc1,
    const float* __restrict__ bc1, const float* __restrict__ Wc2,
    const float* __restrict__ bc2,
    const float* __restrict__ xcomp, const float* __restrict__ masks,
    const unsigned short* __restrict__ wbf,
    const float* __restrict__ wdiag, const float* __restrict__ bfeat,
    const float* __restrict__ Wnl1, const float* __restrict__ bnl1,
    const float* __restrict__ Wnl2, const float* __restrict__ bnl2,
    float* __restrict__ feat_out,
    const unsigned short* __restrict__ wgf, const unsigned short* __restrict__ wgb,
    float* __restrict__ gf, float* __restrict__ gb) {
    // GRU LDS
    __shared__ __align__(16) unsigned short hsg[3][2][32];
    __shared__ __align__(16) float gexg[2][2][32][5];
    // ctxMLP LDS
    __shared__ __align__(16) float ss[193];
    __shared__ float h1[64];
    // feat LDS
    __shared__ __align__(16) unsigned short hbs[4][16 * 32];
    __shared__ __align__(16) float ldsx[4][64 * 16];
    __shared__ __align__(16) float fls[4][16 * 65];

    int bx = blockIdx.x;
    int tid = threadIdx.x;

    if (bx < 64) {
        // ================= GRU =================
        int b0 = bx * 2;
        int g = tid >> 6;
        int lane = tid & 63;
        int s = lane >> 5, n = lane & 31;
        if (g == 3) {
            for (int t = 0; t < NT; t++) block_sync_lds();
            return;
        }
        int b = b0 + s;
        const __half2 zh2 = __float2half2_rn(0.f);
        int4 w4[4];
        {
            const int4* wp = (const int4*)(whhg_h + (size_t)(g * 32 + n) * 32);
            #pragma unroll
            for (int q = 0; q < 4; q++) w4[q] = wp[q];
        }
        const __half2* w2 = (const __half2*)w4;
        float bh = bhh[g * 32 + n];
        int len = lengths[b];
        float hprev = 0.f, hn = 0.f;
        hsg[g][s][n] = f2h(0.f);
        const float* gbase = gg_t + (size_t)b * NT * 96;
        #define GGIDX(T) ((size_t)(T) * 96 + g * 32 + n)
        float gi0 = gbase[GGIDX(0)];
        float gi1 = gbase[GGIDX(1)];
        float gi2 = gbase[GGIDX(2)];
        float gi3 = gbase[GGIDX(3)];
        wave_lds_fence();
        for (int t = 0; t < 252; t += 4) {
            GRU_STEP(t, gi0)
            gi0 = gbase[GGIDX(t + 4)];
            GRU_STEP(t + 1, gi1)
            gi1 = gbase[GGIDX(t + 5)];
            GRU_STEP(t + 2, gi2)
            gi2 = gbase[GGIDX(t + 6)];
            GRU_STEP(t + 3, gi3)
            gi3 = gbase[GGIDX(t + 7)];
        }
        GRU_STEP(252, gi0)
        GRU_STEP(253, gi1)
        GRU_STEP(254, gi2)
        GRU_STEP(255, gi3)
        #undef GGIDX
        if (g == 0) ctx[(b0 + s) * 64 + 32 + n] = hn;
    } else if (bx < 192) {
        // ================= ctx MLP =================
        if (tid >= 64) return;
        int b = bx - 64;
        ss[tid] = stats[b * 256 + tid];
        ss[64 + tid] = stats[b * 256 + 64 + tid];
        ss[128 + tid] = stats[b * 256 + 128 + tid];
        if (tid == 0) ss[192] = stats[b * 256 + 192];
        wave_lds_fence();
        float acc = bc1[tid];
        const float* w = Wc1 + (size_t)tid * 193;
        for (int k = 0; k < 193; k++) acc = fmaf(w[k], ss[k], acc);
        h1[tid] = fmaxf(acc, 0.f);
        wave_lds_fence();
        if (tid < 32) {
            float a = bc2[tid];
            const float* w2 = Wc2 + tid * 64;
            for (int k = 0; k < 64; k++) a = fmaf(w2[k], h1[k], a);
            ctx[b * 64 + tid] = a;
        }
    } else if (bx < 448) {
        // ================= feat MLP half A =================
        int wave = tid >> 6; int lane = tid & 63;
        FEAT_BODY((bx - 192) * 64 + wave * 16)
    } else {
        // ================= LSTM input-gate GEMM (gf, gb), col-major coalesced stores =================
        int wave = tid >> 6, lane = tid & 63;
        int bt0 = (bx - 448) * 64 + wave * 16;
        int r = lane & 15, kc = lane >> 4;
        const float* xr = xcomp + (size_t)(bt0 + r) * NV + kc * 8;
        const float* mr = masks + (size_t)(bt0 + r) * NV + kc * 8;
        short8 af0 = pack8(*(const float4*)(xr), *(const float4*)(xr + 4));
        short8 af1 = pack8(*(const float4*)(xr + 32), *(const float4*)(xr + 36));
        short8 af2 = pack8(*(const float4*)(mr), *(const float4*)(mr + 4));
        short8 af3 = pack8(*(const float4*)(mr + 32), *(const float4*)(mr + 36));
        #pragma unroll 4
        for (int nt = 0; nt < 16; nt++) {
            const unsigned short* w = wgf + (size_t)(nt * 16 + r) * 128 + kc * 8;
            f32x4 acc = {0.f, 0.f, 0.f, 0.f};
            acc = __builtin_amdgcn_mfma_f32_16x16x32_bf16(af0, *(const short8*)(w), acc, 0, 0, 0);
            acc = __builtin_amdgcn_mfma_f32_16x16x32_bf16(af1, *(const short8*)(w + 32), acc, 0, 0, 0);
            acc = __builtin_amdgcn_mfma_f32_16x16x32_bf16(af2, *(const short8*)(w + 64), acc, 0, 0, 0);
            acc = __builtin_amdgcn_mfma_f32_16x16x32_bf16(af3, *(const short8*)(w + 96), acc, 0, 0, 0);
            int col = nt * 16 + r;
            #pragma unroll
            for (int i = 0; i < 4; i++)
                gf[(size_t)(bt0 + kc * 4 + i) * 256 + col] = acc[i];
        }
        #pragma unroll 4
        for (int nt = 0; nt < 16; nt++) {
            const unsigned short* w = wgb + (size_t)(nt * 16 + r) * 128 + kc * 8;
            f32x4 acc = {0.f, 0.f, 0.f, 0.f};
            acc = __builtin_amdgcn_mfma_f32_16x16x32_bf16(af0, *(const short8*)(w), acc, 0, 0, 0);
            acc = __builtin_amdgcn_mfma_f32_16x16x32_bf16(af1, *(const short8*)(w + 32), acc, 0, 0, 0);
            acc = __builtin_amdgcn_mfma_f32_16x16x32_bf16(af2, *(const short8*)(w + 64), acc, 0, 0, 0);
            acc = __builtin_amdgcn_mfma_f32_16x16x32_bf16(af3, *(const short8*)(w + 96), acc, 0, 0, 0);
            int col = nt * 16 + r;
            #pragma unroll
            for (int i = 0; i < 4; i++)
                gb[(size_t)(bt0 + kc * 4 + i) * 256 + col] = acc[i];
        }
    }
}

// ---------------- K6: LSTM (blocks 0..255, inlined cterm/hinit) + feat half B (256..511) ----------------
#define LSTM_STEP(S, GIN) { \
    const int s_ = (S); const int p_ = s_ & 1; \
    int4 raw_[8]; \
    const int4* hp_ = (const int4*)hs[g]; \
    _Pragma("unroll") for (int q = 0; q < 8; q++) raw_[q] = hp_[q]; \
    const __half2* hhv_ = (const __half2*)raw_; \
    __half2 a0_ = zh2, a1_ = zh2, a2_ = zh2, a3_ = zh2; \
    _Pragma("unroll") for (int q = 0; q < 32; q += 4) { \
        a0_ = __hfma2(w2[q],     hhv_[q],     a0_); \
        a1_ = __hfma2(w2[q + 1], hhv_[q + 1], a1_); \
        a2_ = __hfma2(w2[q + 2], hhv_[q + 2], a2_); \
        a3_ = __hfma2(w2[q + 3], hhv_[q + 3], a3_); } \
    __half2 sA_ = __hadd2(__hadd2(a0_, a1_), __hadd2(a2_, a3_)); \
    float d_ = __low2float(sA_) + __high2float(sA_); \
    gex[p_][n][g] = GIN + ctg + d_; \
    block_sync_lds(); \
    float qx_ = gex[p_][n][0], qy_ = gex[p_][n][1]; \
    float qz_ = gex[p_][n][2], qw_ = gex[p_][n][3]; \
    float ii_ = fsigm(qx_); \
    float ff_ = fsigm(qy_); \
    float gv_ = ftanh(qz_); \
    float oo_ = fsigm(qw_); \
    c = ff_ * c + ii_ * gv_; \
    float hv_ = oo_ * ftanh(c); \
    if (g == 0) { \
        int tout_ = dir ? (NT - 2 - s_) : (s_ + 1); \
        hall[((size_t)b * NT + tout_) * NV + n] = hv_; \
    } \
    hs[g][n] = f2h(hv_); \
    wave_lds_fence(); \
}

__global__ __launch_bounds__(256, 1) void k_lstm(
    const float* __restrict__ gf, const float* __restrict__ gb,
    const float* __restrict__ ctx,
    const unsigned short* __restrict__ whhf_h, const unsigned short* __restrict__ whhb_h,
    const float* __restrict__ Wihf, const float* __restrict__ Wihb,
    const float* __restrict__ bihf, const float* __restrict__ bhhf,
    const float* __restrict__ bihb, const float* __restrict__ bhhb,
    const float* __restrict__ Wini, const float* __restrict__ bini,
    float* __restrict__ out0, float* __restrict__ out1,
    const float* __restrict__ xcomp, const unsigned short* __restrict__ wbf,
    const float* __restrict__ wdiag, const float* __restrict__ bfeat,
    const float* __restrict__ Wnl1, const float* __restrict__ bnl1,
    const float* __restrict__ Wnl2, const float* __restrict__ bnl2,
    float* __restrict__ feat_out) {
    // LSTM LDS
    __shared__ __align__(16) unsigned short hs[4][64];
    __shared__ __align__(16) float gex[2][64][5];
    __shared__ __align__(16) float sctx[64];
    __shared__ __align__(16) float sh0[64];
    // feat LDS
    __shared__ __align__(16) unsigned short hbs[4][16 * 32];
    __shared__ __align__(16) float ldsx[4][64 * 16];
    __shared__ __align__(16) float fls[4][16 * 65];

    int bx = blockIdx.x;
    int tid = threadIdx.x;

    if (bx >= 256) {
        // ================= feat MLP half B =================
        int wave = tid >> 6; int lane = tid & 63;
        FEAT_BODY((bx - 256) * 64 + 16384 + wave * 16)
        return;
    }

    int dir = bx >> 7; int b = bx & 127;
    int g = tid >> 6;
    int n = tid & 63;
    const float* gates = dir ? gb : gf;
    const unsigned short* wsrc = dir ? whhb_h : whhf_h;
    float* hall = dir ? out1 : out0;
    const __half2 zh2 = __float2half2_rn(0.f);
    int4 w4[8];
    {
        const int4* wp = (const int4*)(wsrc + (size_t)(g * 64 + n) * 64);
        #pragma unroll
        for (int q = 0; q < 8; q++) w4[q] = wp[q];
    }
    const __half2* w2 = (const __half2*)w4;
    // ---- prologue: gate prefetch + in-block cterm/hinit ----
    // gates layout: [bt][col] with col = g*64 + n = tid  →  fully coalesced reads
    size_t gbase = (size_t)b * NT * 256 + tid;
    #define GIDX(S) (gbase + (size_t)(dir ? (NT - 1 - (S)) : (S)) * 256)
    float gi0 = gates[GIDX(0)];
    float gi1 = gates[GIDX(1)];
    float gi2 = gates[GIDX(2)];
    float gi3 = gates[GIDX(3)];
    if (tid < 64) sctx[tid] = ctx[b * 64 + tid];
    __syncthreads();
    float ctg;
    {
        const float4* wc = (const float4*)((dir ? Wihb : Wihf) + (size_t)tid * 192 + 128);
        float bias = dir ? (bihb[tid] + bhhb[tid]) : (bihf[tid] + bhhf[tid]);
        const float4* c4 = (const float4*)sctx;
        float4 a = {0, 0, 0, 0};
        #pragma unroll
        for (int q = 0; q < 16; q++) dot4(a, wc[q], c4[q]);
        ctg = bias + a.x + a.y + a.z + a.w;
    }
    if (tid < 64) {
        const float4* wi = (const float4*)(Wini + (size_t)(dir * 64 + tid) * 64);
        const float4* c4 = (const float4*)sctx;
        float4 a = {0, 0, 0, 0};
        #pragma unroll
        for (int q = 0; q < 16; q++) dot4(a, wi[q], c4[q]);
        sh0[tid] = bini[dir * 64 + tid] + a.x + a.y + a.z + a.w;
    }
    __syncthreads();
    float c;
    {
        float h0 = sh0[n];
        c = ftanh(h0);
        hs[g][n] = f2h(h0);
        if (g == 0) {
            int t0 = dir ? (NT - 1) : 0;
            hall[((size_t)b * NT + t0) * NV + n] = h0;
        }
    }
    wave_lds_fence();
    for (int sx = 0; sx < 252; sx += 4) {
        LSTM_STEP(sx, gi0)
        gi0 = gates[GIDX(sx + 4)];
        LSTM_STEP(sx + 1, gi1)
        gi1 = gates[GIDX(sx + 5)];
        LSTM_STEP(sx + 2, gi2)
        gi2 = gates[GIDX(sx + 6)];
        LSTM_STEP(sx + 3, gi3)
        gi3 = gates[GIDX(sx + 7)];
    }
    LSTM_STEP(252, gi0)
    LSTM_STEP(253, gi1)
    LSTM_STEP(254, gi2)
    #undef GIDX
}

// ---------------- K_post: fused rnn_imp GEMM + beta GEMM + fusion + scaling ----------------
__global__ __launch_bounds__(256) void k_post(
    const unsigned short* __restrict__ gam, const float* __restrict__ masks,
    const unsigned short* __restrict__ wri_bf, const unsigned short* __restrict__ wfu_bf,
    const float* __restrict__ bri, const float* __restrict__ bfu,
    const float* __restrict__ mmn_ws, const float* __restrict__ minv,
    float* out0, float* out1, float* out2) {
    int wave = threadIdx.x >> 6, lane = threadIdx.x & 63;
    int bt0 = blockIdx.x * 64 + wave * 16;
    int r = lane & 15, kc = lane >> 4;
    int b = bt0 >> 8;
    const float* h0r = out0 + (size_t)(bt0 + r) * NV + kc * 8;
    const float* h1r = out1 + (size_t)(bt0 + r) * NV + kc * 8;
    const unsigned short* gr = gam + (size_t)(bt0 + r) * NV + kc * 8;
    const float* mr  = masks + (size_t)(bt0 + r) * NV + kc * 8;
    short8 A0 = pack8(*(const float4*)(h0r), *(const float4*)(h0r + 4));
    short8 A1 = pack8(*(const float4*)(h0r + 32), *(const float4*)(h0r + 36));
    short8 A2 = pack8(*(const float4*)(h1r), *(const float4*)(h1r + 4));
    short8 A3 = pack8(*(const float4*)(h1r + 32), *(const float4*)(h1r + 36));
    short8 G0 = *(const short8*)(gr);
    short8 G1 = *(const short8*)(gr + 32);
    short8 M0 = pack8(*(const float4*)(mr), *(const float4*)(mr + 4));
    short8 M1 = pack8(*(const float4*)(mr + 32), *(const float4*)(mr + 36));
    #pragma unroll
    for (int nt = 0; nt < 4; nt++) {
        int n = nt * 16 + r;
        const unsigned short* wr = wri_bf + (size_t)n * 128 + kc * 8;
        const unsigned short* wf = wfu_bf + (size_t)n * 128 + kc * 8;
        float bi = bri[n], bf_ = bfu[n];
        f32x4 racc = {bi, bi, bi, bi};
        f32x4 bacc = {bf_, bf_, bf_, bf_};
        racc = __builtin_amdgcn_mfma_f32_16x16x32_bf16(A0, *(const short8*)(wr), racc, 0, 0, 0);
        racc = __builtin_amdgcn_mfma_f32_16x16x32_bf16(A1, *(const short8*)(wr + 32), racc, 0, 0, 0);
        racc = __builtin_amdgcn_mfma_f32_16x16x32_bf16(A2, *(const short8*)(wr + 64), racc, 0, 0, 0);
        racc = __builtin_amdgcn_mfma_f32_16x16x32_bf16(A3, *(const short8*)(wr + 96), racc, 0, 0, 0);
        bacc = __builtin_amdgcn_mfma_f32_16x16x32_bf16(G0, *(const short8*)(wf), bacc, 0, 0, 0);
        bacc = __builtin_amdgcn_mfma_f32_16x16x32_bf16(G1, *(const short8*)(wf + 32), bacc, 0, 0, 0);
        bacc = __builtin_amdgcn_mfma_f32_16x16x32_bf16(M0, *(const short8*)(wf + 64), bacc, 0, 0, 0);
        bacc = __builtin_amdgcn_mfma_f32_16x16x32_bf16(M1, *(const short8*)(wf + 96), bacc, 0, 0, 0);
        float mm = mmn_ws[b * NV + n], mn = minv[b * NV + n];
        #pragma unroll
        for (int i = 0; i < 4; i++) {
            int row = bt0 + kc * 4 + i;
            size_t idx = (size_t)row * NV + n;
            float rn = racc[i];
            float beta = fsigm(bacc[i]);
            float ft = out2[idx];
            float fin = beta * ft + (1.0f - beta) * rn;
            out0[idx] = fmaf(rn, mm, mn);
            out1[idx] = fmaf(ft, mm, mn);
            out2[idx] = fmaf(fin, mm, mn);
        }
    }
}

extern "C" void kernel_launch(void* const* d_in, const int* in_sizes, int n_in,
                              void* d_out, int out_size, void* d_ws, size_t ws_size,
                              hipStream_t stream) {
    const int*   lengths  = (const int*)d_in[0];
    const float* values   = (const float*)d_in[1];
    const float* masks    = (const float*)d_in[2];
    const float* deltas   = (const float*)d_in[3];
    const float* min_vals = (const float*)d_in[4];
    const float* max_vals = (const float*)d_in[5];
    const float* W_decay  = (const float*)d_in[6];
    const float* b_decay  = (const float*)d_in[7];
    const float* W_feat   = (const float*)d_in[8];
    const float* b_feat   = (const float*)d_in[9];
    const float* W_nl1    = (const float*)d_in[10];
    const float* b_nl1    = (const float*)d_in[11];
    const float* W_nl2    = (const float*)d_in[12];
    const float* b_nl2    = (const float*)d_in[13];
    const float* Wc1      = (const float*)d_in[14];
    const float* bc1      = (const float*)d_in[15];
    const float* Wc2      = (const float*)d_in[16];
    const float* bc2      = (const float*)d_in[17];
    const float* W_ih_g   = (const float*)d_in[18];
    const float* W_hh_g   = (const float*)d_in[19];
    const float* b_ih_g   = (const float*)d_in[20];
    const float* b_hh_g   = (const float*)d_in[21];
    const float* W_init   = (const float*)d_in[22];
    const float* b_init   = (const float*)d_in[23];
    const float* W_ih_f   = (const float*)d_in[24];
    const float* W_hh_f   = (const float*)d_in[25];
    const float* b_ih_f   = (const float*)d_in[26];
    const float* b_hh_f   = (const float*)d_in[27];
    const float* W_ih_b   = (const float*)d_in[28];
    const float* W_hh_b   = (const float*)d_in[29];
    const float* b_ih_b   = (const float*)d_in[30];
    const float* b_hh_b   = (const float*)d_in[31];
    const float* W_ri     = (const float*)d_in[32];
    const float* b_ri     = (const float*)d_in[33];
    const float* W_fu     = (const float*)d_in[34];
    const float* b_fu     = (const float*)d_in[35];

    float* ws = (float*)d_ws;
    float* xcomp  = ws;                     // 2097152
    unsigned short* gam = (unsigned short*)(ws + 2097152);  // 2097152 u16 (4 MB)
    unsigned short* wri_bf = (unsigned short*)(ws + 4194304); // 8192 u16
    unsigned short* wfu_bf = (unsigned short*)(ws + 4198400); // 8192 u16
    float* stats  = ws + 6291456;           // 32768
    float* mmn    = ws + 6324224;           // 8192
    float* nmeans = ws + 6332416;           // 8192
    float* ctx    = ws + 6340608;           // 8192
    unsigned short* wbf = (unsigned short*)(ws + 6365184);  // 131072 u16
    float* wdiag  = ws + 6430720;           // 2048
    unsigned short* wgf = (unsigned short*)(ws + 6432768);  // 32768 u16
    unsigned short* wgb = (unsigned short*)(ws + 6449152);  // 32768 u16
    unsigned short* wgg = (unsigned short*)(ws + 6465536);  // 12288 u16
    unsigned short* whhf_h = (unsigned short*)(ws + 6471680); // 16384 u16
    unsigned short* whhb_h = (unsigned short*)(ws + 6479872); // 16384 u16
    unsigned short* whhg_h = (unsigned short*)(ws + 6488064); // 3072 u16
    float* gates_f = ws + 6555136;          // 8388608
    float* gates_b = ws + 14943744;         // 8388608
    float* gates_g = ws + 23332352;         // 3145728  (end ≈ 106 MB)

    float* out0 = (float*)d_out;
    float* out1 = out0 + NBTV;
    float* out2 = out0 + 2 * NBTV;

    k_prep<<<512, 256, 0, stream>>>(W_feat, W_ih_f, W_ih_b, W_ih_g, W_hh_f, W_hh_b, W_hh_g,
                                    W_ri, W_fu,
                                    wbf, wdiag, wgf, wgb, wgg, whhf_h, whhb_h, whhg_h,
                                    wri_bf, wfu_bf);
    k_fill<<<NB, 256, 0, stream>>>(lengths, values, masks, deltas, min_vals, max_vals,
                                   W_decay, b_decay, stats, mmn, nmeans, xcomp, gam,
                                   wgg, b_ih_g, gates_g);
    k_mid<<<960, 256, 0, stream>>>(gates_g, lengths, whhg_h, b_hh_g, ctx,
                                   stats, Wc1, bc1, Wc2, bc2,
                                   xcomp, masks, wbf, wdiag, b_feat, W_nl1, b_nl1, W_nl2, b_nl2, out2,
                                   wgf, wgb, gates_f, gates_b);
    k_lstm<<<512, 256, 0, stream>>>(gates_f, gates_b, ctx, whhf_h, whhb_h,
                                    W_ih_f, W_ih_b, b_ih_f, b_hh_f, b_ih_b, b_hh_b,
                                    W_init, b_init, out0, out1,
                                    xcomp, wbf, wdiag, b_feat, W_nl1, b_nl1, W_nl2, b_nl2, out2);
    k_post<<<NBT / 64, 256, 0, stream>>>(gam, masks, wri_bf, wfu_bf, b_ri, b_fu, mmn, min_vals,
                                         out0, out1, out2);
}